// Round 11
// baseline (3785.610 us; speedup 1.0000x reference)
//
#include <hip/hip_runtime.h>
#include <hip/hip_bf16.h>
#include <hip/hip_fp16.h>

// GCN 3-layer. R11: (1) agg L2-locality: bucket_csr ranks by (dlow, src>>14)
// via 1024 LDS sub-counters -> each row's edges ordered by src-quartile ->
// concurrent waves phase through 3.2MB working-set windows (fits 4MB/XCD L2).
// (2) gemm1 transposes W1 in-staging (no Wt1) and is co-dispatched with
// part_count + Wt2/3 prep -> off the critical path. (3) part_scatter
// self-scans the counts array (300KB, L2) for its base values -> the 3
// scan dispatches deleted. 12 -> 9 dispatches. agg structure unchanged
// (scalar ep loads, byte-offset gathers, UN=24, service-rate ~3.7TB/s).

#define K_IN 128              // all layers have in_features == 128
#define FIX_SCALE 8388608.0f  // 2^23 fixed point for ew sums
#define CE 4096               // edges per partition block

typedef _Float16 f16x8 __attribute__((ext_vector_type(8)));
typedef float f32x4 __attribute__((ext_vector_type(4)));

// ---------- shared gemm tile body ----------
// H[64 x NOUT](fp16) = X[64 x 128] @ W for one tile. Ws must be pre-staged
// by caller region; this stages X and runs MFMA. Layout pads to 136 halves.
template <int NOUT, bool XF16>
__device__ __forceinline__ void gemm_tile(const void* __restrict__ Xv,
                                          _Float16 (*Xs)[136],
                                          _Float16 (*Ws)[136],
                                          _Float16* __restrict__ H,
                                          int n, int tile, int t) {
    constexpr int CTW = NOUT / 64;  // col-tiles per wave
    int row0 = tile * 64;
    if (XF16) {
        const _Float16* X = (const _Float16*)Xv;
        for (int i = t * 8; i < 64 * K_IN; i += 2048) {
            int r = i >> 7, k = i & 127;
            int row = row0 + r;
            uint4 v = make_uint4(0u, 0u, 0u, 0u);
            if (row < n) v = *(const uint4*)(X + (size_t)row * K_IN + k);
            *(uint4*)&Xs[r][k] = v;
        }
    } else {
        const float* X = (const float*)Xv;
        for (int i = t * 4; i < 64 * K_IN; i += 1024) {
            int r = i >> 7, k = i & 127;
            int row = row0 + r;
            float4 x4 = make_float4(0.f, 0.f, 0.f, 0.f);
            if (row < n) x4 = *(const float4*)(X + (size_t)row * K_IN + k);
            union { _Float16 h[4]; uint2 u; } uu;
            uu.h[0] = (_Float16)x4.x; uu.h[1] = (_Float16)x4.y;
            uu.h[2] = (_Float16)x4.z; uu.h[3] = (_Float16)x4.w;
            *(uint2*)&Xs[r][k] = uu.u;
        }
    }
    __syncthreads();

    int lane = t & 63, w = t >> 6;
    int m = lane & 15, g = lane >> 4;
    f32x4 acc[4][CTW];
#pragma unroll
    for (int mt = 0; mt < 4; mt++)
#pragma unroll
        for (int ct = 0; ct < CTW; ct++) acc[mt][ct] = (f32x4){0.f, 0.f, 0.f, 0.f};

#pragma unroll
    for (int kt = 0; kt < 4; kt++) {
        int kb = kt * 32 + g * 8;
        f16x8 a[4];
#pragma unroll
        for (int mt = 0; mt < 4; mt++) a[mt] = *(const f16x8*)&Xs[mt * 16 + m][kb];
#pragma unroll
        for (int ct = 0; ct < CTW; ct++) {
            int nn = w * (16 * CTW) + ct * 16 + m;
            f16x8 b = *(const f16x8*)&Ws[nn][kb];
#pragma unroll
            for (int mt = 0; mt < 4; mt++)
                acc[mt][ct] = __builtin_amdgcn_mfma_f32_16x16x32_f16(a[mt], b, acc[mt][ct], 0, 0, 0);
        }
    }

#pragma unroll
    for (int mt = 0; mt < 4; mt++) {
#pragma unroll
        for (int r = 0; r < 4; r++) {
            int row = row0 + mt * 16 + g * 4 + r;
            if (row < n) {
#pragma unroll
                for (int ct = 0; ct < CTW; ct++)
                    H[(size_t)row * NOUT + w * (16 * CTW) + ct * 16 + m] =
                        (_Float16)acc[mt][ct][r];
            }
        }
    }
}

// ---------- dispatch 1: part_count || gemm1 (W1 transposed in-staging) || Wt2/3 prep ----------
__global__ __launch_bounds__(256) void mega1(
    const int* __restrict__ dst, int* __restrict__ counts,
    unsigned short* __restrict__ lrank, int nb, int nblk, int e,
    const float* __restrict__ x, const float* __restrict__ W1,
    _Float16* __restrict__ bufH, int n, int gGemm,
    const float* __restrict__ W2, const float* __restrict__ W3,
    _Float16* __restrict__ Wt2, _Float16* __restrict__ Wt3) {
    __shared__ _Float16 Xs[64][136];
    __shared__ _Float16 Ws[128][136];
    __shared__ int c[256];
    int t = threadIdx.x, blk = blockIdx.x;

    if (blk < nblk) {  // ---- bucket histogram + local rank ----
        c[t] = 0;
        __syncthreads();
        int b0 = blk * CE;
#pragma unroll
        for (int j = 0; j < 16; j++) {
            int i = b0 + j * 256 + t;
            if (i < e) {
                int b = dst[i] >> 8;
                int r = atomicAdd(&c[b], 1);  // LDS atomic
                lrank[i] = (unsigned short)r;
            }
        }
        __syncthreads();
        if (t < nb) counts[(size_t)t * nblk + blk] = c[t];
        return;
    }
    if (blk < nblk + gGemm) {  // ---- gemm1 tile: stage W1 fp32 transposed ----
        for (int i = t; i < 128 * 128; i += 256) {
            int k = i >> 7, nn = i & 127;
            Ws[nn][k] = (_Float16)W1[i];  // 8-way LDS write conflict, one-time
        }
        gemm_tile<128, false>(x, Xs, Ws, bufH, n, blk - nblk, t);
        return;
    }
    // ---- Wt2/Wt3 prep (fp16 transposed) ----
    int i = (blk - nblk - gGemm) * 256 + t;
    if (i < 128 * 128) {
        int k = i >> 7, nn = i & 127;
        Wt2[(size_t)nn * 128 + k] = (_Float16)W2[i];
    } else if (i < 128 * 128 + 64 * 128) {
        int l = i - 128 * 128, k = l >> 6, nn = l & 63;
        Wt3[(size_t)nn * 128 + k] = (_Float16)W3[l];
    }
}

// ---------- dispatch 2: scatter into bucket order; base self-scanned from counts ----------
__global__ __launch_bounds__(256) void part_scatter(const int* __restrict__ src,
                                                    const int* __restrict__ dst,
                                                    const float* __restrict__ ew,
                                                    const int* __restrict__ counts,
                                                    const unsigned short* __restrict__ lrank,
                                                    int2* __restrict__ arr1,
                                                    int nb, int nblk, int e) {
    __shared__ int tsum[256];
    __shared__ int lbase[256];  // nb <= 256 entries used
    int t = threadIdx.x, blk = blockIdx.x;
    int m = nb * nblk;
    int ch = (m + 255) / 256;
    int s0 = t * ch, s1 = min(s0 + ch, m);
    // pass A: per-thread chunk sums -> exclusive prefix
    int loc = 0;
    for (int i = s0; i < s1; i++) loc += counts[i];
    tsum[t] = loc;
    __syncthreads();
    for (int off = 1; off < 256; off <<= 1) {
        int cur = tsum[t];
        int add = (t >= off) ? tsum[t - off] : 0;
        __syncthreads();
        tsum[t] = cur + add;
        __syncthreads();
    }
    int run = (t == 0) ? 0 : tsum[t - 1];
    // pass B: walk chunk, capture prefix at idx == b*nblk + blk
    if (s0 < m) {
        int b = s0 / nblk, r = s0 - b * nblk;
        for (int i = s0; i < s1; i++) {
            if (r == blk) lbase[b] = run;
            run += counts[i];
            if (++r == nblk) { r = 0; b++; }
        }
    }
    __syncthreads();
    // edge scatter
    int b0 = blk * CE;
#pragma unroll
    for (int j = 0; j < 16; j++) {
        int i = b0 + j * 256 + t;
        if (i < e) {
            int d = dst[i];
            int pos = lbase[d >> 8] + lrank[i];
            arr1[pos] = make_int2((src[i] << 8) | (d & 255), __float_as_int(ew[i]));
        }
    }
}

// ---------- dispatch 3: per-bucket CSR finalize, rank by (dlow, src-quartile) ----------
__global__ __launch_bounds__(1024) void bucket_csr(const int2* __restrict__ arr1,
                                                   const int* __restrict__ counts,
                                                   unsigned short* __restrict__ rank2,
                                                   float* __restrict__ dinv,
                                                   int* __restrict__ row_ptr,
                                                   int2* __restrict__ ep,
                                                   int nb, int nblk, int n, int e) {
    __shared__ unsigned long long pk[1024];  // cnt lo32 | fx-sum hi32, per (dlow,srcq)
    __shared__ int nbase[1024];
    __shared__ int ss[1024];
    __shared__ float ldsdinv[256];
    __shared__ int begs[2];
    int t = threadIdx.x, b = blockIdx.x;
    // bucket [beg,end) from counts prefix: beg = sum over buckets < b (self-scan, L2)
    if (t < 2) {
        int lim = (b + t) * nblk;  // beg: idx < b*nblk; end: idx < (b+1)*nblk
        int s = 0;
        for (int i = t == 0 ? 0 : (b * nblk); i < lim; i++) s += counts[i];
        begs[t] = s;
    }
    pk[t] = 0ULL;
    __syncthreads();
    if (t == 1) begs[1] += begs[0];
    __syncthreads();
    int beg = begs[0];
    int end = (b + 1 < nb) ? begs[1] : e;
    for (int i = beg + t; i < end; i += 1024) {
        int2 a = arr1[i];
        int ld4 = ((a.x & 255) << 2) | ((a.x >> 22) & 3);  // (dlow, src>>14)
        float w = __int_as_float(a.y);
        unsigned long long fx = (unsigned long long)(unsigned int)(w * FIX_SCALE + 0.5f);
        unsigned long long old = atomicAdd(&pk[ld4], (fx << 32) | 1ULL);  // LDS
        rank2[i] = (unsigned short)(old & 0xffffffffULL);
    }
    __syncthreads();
    int cnt = (int)(pk[t] & 0xffffffffULL);
    ss[t] = cnt;
    __syncthreads();
    for (int off = 1; off < 1024; off <<= 1) {
        int cur = ss[t];
        int add = (t >= off) ? ss[t - off] : 0;
        __syncthreads();
        ss[t] = cur + add;
        __syncthreads();
    }
    nbase[t] = ss[t] - cnt;
    __syncthreads();
    if (t < 256) {
        int d = b * 256 + t;
        if (d < n) {
            unsigned int fxs = 0;
#pragma unroll
            for (int q = 0; q < 4; q++) fxs += (unsigned int)(pk[t * 4 + q] >> 32);
            float dv = rsqrtf(1.0f + (float)fxs * (1.0f / FIX_SCALE));  // +1 self loop
            dinv[d] = dv;
            ldsdinv[t] = dv;
            row_ptr[d] = beg + nbase[t * 4];
        }
    }
    __syncthreads();
    for (int i = beg + t; i < end; i += 1024) {
        int2 a = arr1[i];
        int dlow = a.x & 255;
        int ld4 = (dlow << 2) | ((a.x >> 22) & 3);
        int pos = beg + nbase[ld4] + rank2[i];
        float w = __int_as_float(a.y) * ldsdinv[dlow];
        ep[pos] = make_int2(a.x >> 8, __float_as_int(w));  // src index, w*dinv[dst]
    }
}

// ---------- dispatch 4: ep -> (src byte offset, w*dinv[src]); row_ptr[N]=E ----------
__global__ void val_kernel(int2* __restrict__ ep, const float* __restrict__ dinv,
                           int* __restrict__ row_ptr, int n, int e) {
    int i = blockIdx.x * blockDim.x + threadIdx.x;
    if (i == 0) row_ptr[n] = e;
    if (i >= e) return;
    int2 a = ep[i];
    float w = __int_as_float(a.y) * dinv[a.x];
    ep[i] = make_int2(a.x << 8, __float_as_int(w));  // src*256 B (fp16 row, F=128)
}

// ---------- standalone MFMA gemm (layers 2,3: fp16 X, fp16 Wt) ----------
template <int NOUT>
__global__ __launch_bounds__(256) void mfma_gemm(const _Float16* __restrict__ X,
                                                 const _Float16* __restrict__ Wt,
                                                 _Float16* __restrict__ H, int n) {
    __shared__ _Float16 Xs[64][136];
    __shared__ _Float16 Ws[NOUT][136];
    int t = threadIdx.x;
    for (int i = t * 8; i < NOUT * K_IN; i += 2048) {
        int nn = i >> 7, k = i & 127;
        *(uint4*)&Ws[nn][k] = *(const uint4*)&Wt[i];
    }
    gemm_tile<NOUT, true>(X, Xs, Ws, H, n, blockIdx.x, t);
}

// ---------- aggregation: scalar ep loads, byte-offset gathers, fp32 accum ----------
template <int F, bool RELU, bool OF16>
__global__ __launch_bounds__(256) void agg_kernel(const __half* __restrict__ H,
                                                  const int* __restrict__ row_ptr,
                                                  const int2* __restrict__ ep,
                                                  const float* __restrict__ dinv,
                                                  const float* __restrict__ bias,
                                                  void* __restrict__ outv, int n) {
    constexpr int UN = 24;
    int wid = threadIdx.x >> 6;
    int lane = threadIdx.x & 63;
    int node = blockIdx.x * 4 + wid;
    if (node >= n) return;

    int start = __builtin_amdgcn_readfirstlane(row_ptr[node]);
    int end   = __builtin_amdgcn_readfirstlane(row_ptr[node + 1]);
    float di = dinv[node];
    float sw = di * di;

    const unsigned lb = (unsigned)lane * (F == 128 ? 4u : 2u);  // lane byte offset

    float a0, a1;
    if (F == 128) {
        float2 s2 = __half22float2(((const __half2*)(H + (size_t)node * 128))[lane]);
        a0 = s2.x * sw; a1 = s2.y * sw;
    } else {
        a0 = __half2float(H[(size_t)node * 64 + lane]) * sw; a1 = 0.f;
    }

    int len = end - start;
    int nf = len / UN;
    for (int b = 0; b < nf; b++) {
        int p0 = start + b * UN;
        int2 e[UN];
#pragma unroll
        for (int u = 0; u < UN; u++) e[u] = ep[p0 + u];  // uniform addr -> s_load
        __half2 v2[UN];
        __half v1[UN];
#pragma unroll
        for (int u = 0; u < UN; u++) {
            unsigned off = (unsigned)e[u].x;
            if (F == 64) off >>= 1;
            if (F == 128) v2[u] = *(const __half2*)((const char*)H + (off + lb));
            else          v1[u] = *(const __half*)((const char*)H + (off + lb));
        }
#pragma unroll
        for (int u = 0; u < UN; u++) {
            float w = __int_as_float(e[u].y);
            if (F == 128) {
                float2 f = __half22float2(v2[u]);
                a0 += w * f.x; a1 += w * f.y;
            } else {
                a0 += w * __half2float(v1[u]);
            }
        }
    }
    int base = start + nf * UN;
    if (base < end) {  // single predicated tail batch (uniform predicates)
        int2 e[UN];
#pragma unroll
        for (int u = 0; u < UN; u++) {
            int p = base + u;
            int q = (p < end) ? p : end - 1;
            int2 t2 = ep[q];
            if (p >= end) t2.y = 0;
            e[u] = t2;
        }
        __half2 v2[UN];
        __half v1[UN];
#pragma unroll
        for (int u = 0; u < UN; u++) {
            unsigned off = (unsigned)e[u].x;
            if (F == 64) off >>= 1;
            if (F == 128) v2[u] = *(const __half2*)((const char*)H + (off + lb));
            else          v1[u] = *(const __half*)((const char*)H + (off + lb));
        }
#pragma unroll
        for (int u = 0; u < UN; u++) {
            float w = __int_as_float(e[u].y);
            if (F == 128) {
                float2 f = __half22float2(v2[u]);
                a0 += w * f.x; a1 += w * f.y;
            } else {
                a0 += w * __half2float(v1[u]);
            }
        }
    }

    if (F == 128) {
        float o0 = a0 + bias[lane * 2];
        float o1 = a1 + bias[lane * 2 + 1];
        if (RELU) { o0 = fmaxf(o0, 0.f); o1 = fmaxf(o1, 0.f); }
        if (OF16) {
            ((__half2*)outv)[(size_t)node * 64 + lane] = __floats2half2_rn(o0, o1);
        } else {
            *(float2*)((float*)outv + (size_t)node * 128 + lane * 2) = make_float2(o0, o1);
        }
    } else {
        float o = a0 + bias[lane];
        if (RELU) o = fmaxf(o, 0.f);
        if (OF16) ((__half*)outv)[(size_t)node * 64 + lane] = __float2half(o);
        else      ((float*)outv)[(size_t)node * 64 + lane] = o;
    }
}

// ---------- launch ----------

extern "C" void kernel_launch(void* const* d_in, const int* in_sizes, int n_in,
                              void* d_out, int out_size, void* d_ws, size_t ws_size,
                              hipStream_t stream) {
    const float* x   = (const float*)d_in[0];
    const int*   ei  = (const int*)d_in[1];   // int32 (JAX x64 disabled)
    const float* ew  = (const float*)d_in[2];
    const float* W1  = (const float*)d_in[3];
    const float* b1  = (const float*)d_in[4];
    const float* W2  = (const float*)d_in[5];
    const float* b2  = (const float*)d_in[6];
    const float* W3  = (const float*)d_in[7];
    const float* b3  = (const float*)d_in[8];
    float* out = (float*)d_out;

    const int N = in_sizes[0] / K_IN;
    const int E = in_sizes[2];
    const int* src = ei;
    const int* dst = ei + E;

    const int NB   = (N + 255) >> 8;     // buckets, <=256
    const int NBLK = (E + CE - 1) / CE;  // partition blocks
    const int NWT  = (128 * 128 + 64 * 128 + 255) / 256;  // Wt2/3 prep blocks

    char* w = (char*)d_ws;
    auto alloc = [&](size_t bytes) {
        void* p = (void*)w;
        w += (bytes + 255) & ~(size_t)255;
        return p;
    };
    int*            counts = (int*)alloc((size_t)NB * NBLK * 4);
    unsigned short* lrank  = (unsigned short*)alloc((size_t)E * 2);  // reused as rank2
    int2*           arr1   = (int2*)alloc((size_t)E * 8);
    float*          dinv   = (float*)alloc((size_t)N * 4);
    int*            row_ptr= (int*)alloc((size_t)(N + 1) * 4);
    int2*           ep     = (int2*)alloc((size_t)E * 8);
    _Float16*       Wt2    = (_Float16*)alloc(128 * 128 * 2);
    _Float16*       Wt3    = (_Float16*)alloc(64 * 128 * 2);
    _Float16*       bufH   = (_Float16*)alloc((size_t)N * 128 * 2);  // gemm out
    _Float16*       bufX   = (_Float16*)alloc((size_t)N * 128 * 2);  // agg out (fp16)

    int gGemm = (N + 63) / 64;
    int gAgg  = (N + 3) / 4;

    // 1: part_count || gemm1 (x@W1, W1 transposed in-staging) || Wt2/3 prep
    mega1<<<NBLK + gGemm + NWT, 256, 0, stream>>>(dst, counts, lrank, NB, NBLK, E,
                                                  x, W1, bufH, N, gGemm, W2, W3, Wt2, Wt3);
    // 2: scatter (self-scanned bases)
    part_scatter<<<NBLK, 256, 0, stream>>>(src, dst, ew, counts, lrank, arr1, NB, NBLK, E);
    // 3: per-bucket CSR finalize (src-quartile ordering within rows)
    bucket_csr<<<NB, 1024, 0, stream>>>(arr1, counts, lrank, dinv, row_ptr, ep,
                                        NB, NBLK, N, E);
    // 4: val
    val_kernel<<<(E + 255) / 256, 256, 0, stream>>>(ep, dinv, row_ptr, N, E);
    // 5-9: layers
    agg_kernel<128, true, true><<<gAgg, 256, 0, stream>>>((const __half*)bufH, row_ptr, ep,
                                                          dinv, b1, bufX, N);
    mfma_gemm<128><<<gGemm, 256, 0, stream>>>(bufX, Wt2, bufH, N);
    agg_kernel<128, true, true><<<gAgg, 256, 0, stream>>>((const __half*)bufH, row_ptr, ep,
                                                          dinv, b2, bufX, N);
    mfma_gemm<64><<<gGemm, 256, 0, stream>>>(bufX, Wt3, bufH, N);
    agg_kernel<64, false, false><<<gAgg, 256, 0, stream>>>((const __half*)bufH, row_ptr, ep,
                                                           dinv, b3, out, N);
}

// Round 12
// 411.258 us; speedup vs baseline: 9.2049x; 9.2049x over previous
//
#include <hip/hip_runtime.h>
#include <hip/hip_bf16.h>
#include <hip/hip_fp16.h>

// GCN 3-layer. R12: fix R11's 12x regression — bucket_csr's beg/end was a
// 2-thread serial scan over ~76k counts (3465us, occupancy 19%). Now
// part_scatter block 0 (which already computes the full bucket prefix in
// LDS) writes bucket_beg[nb+1] to global; bucket_csr reads 2 ints. All else
// = R11: mega1 (part_count || gemm1 w/ in-staging W1 transpose || Wt2/3),
// self-scanned scatter, src-quartile row ordering, scalar-ep agg UN=24.

#define K_IN 128              // all layers have in_features == 128
#define FIX_SCALE 8388608.0f  // 2^23 fixed point for ew sums
#define CE 4096               // edges per partition block

typedef _Float16 f16x8 __attribute__((ext_vector_type(8)));
typedef float f32x4 __attribute__((ext_vector_type(4)));

// ---------- shared gemm tile body ----------
template <int NOUT, bool XF16>
__device__ __forceinline__ void gemm_tile(const void* __restrict__ Xv,
                                          _Float16 (*Xs)[136],
                                          _Float16 (*Ws)[136],
                                          _Float16* __restrict__ H,
                                          int n, int tile, int t) {
    constexpr int CTW = NOUT / 64;  // col-tiles per wave
    int row0 = tile * 64;
    if (XF16) {
        const _Float16* X = (const _Float16*)Xv;
        for (int i = t * 8; i < 64 * K_IN; i += 2048) {
            int r = i >> 7, k = i & 127;
            int row = row0 + r;
            uint4 v = make_uint4(0u, 0u, 0u, 0u);
            if (row < n) v = *(const uint4*)(X + (size_t)row * K_IN + k);
            *(uint4*)&Xs[r][k] = v;
        }
    } else {
        const float* X = (const float*)Xv;
        for (int i = t * 4; i < 64 * K_IN; i += 1024) {
            int r = i >> 7, k = i & 127;
            int row = row0 + r;
            float4 x4 = make_float4(0.f, 0.f, 0.f, 0.f);
            if (row < n) x4 = *(const float4*)(X + (size_t)row * K_IN + k);
            union { _Float16 h[4]; uint2 u; } uu;
            uu.h[0] = (_Float16)x4.x; uu.h[1] = (_Float16)x4.y;
            uu.h[2] = (_Float16)x4.z; uu.h[3] = (_Float16)x4.w;
            *(uint2*)&Xs[r][k] = uu.u;
        }
    }
    __syncthreads();

    int lane = t & 63, w = t >> 6;
    int m = lane & 15, g = lane >> 4;
    f32x4 acc[4][CTW];
#pragma unroll
    for (int mt = 0; mt < 4; mt++)
#pragma unroll
        for (int ct = 0; ct < CTW; ct++) acc[mt][ct] = (f32x4){0.f, 0.f, 0.f, 0.f};

#pragma unroll
    for (int kt = 0; kt < 4; kt++) {
        int kb = kt * 32 + g * 8;
        f16x8 a[4];
#pragma unroll
        for (int mt = 0; mt < 4; mt++) a[mt] = *(const f16x8*)&Xs[mt * 16 + m][kb];
#pragma unroll
        for (int ct = 0; ct < CTW; ct++) {
            int nn = w * (16 * CTW) + ct * 16 + m;
            f16x8 b = *(const f16x8*)&Ws[nn][kb];
#pragma unroll
            for (int mt = 0; mt < 4; mt++)
                acc[mt][ct] = __builtin_amdgcn_mfma_f32_16x16x32_f16(a[mt], b, acc[mt][ct], 0, 0, 0);
        }
    }

#pragma unroll
    for (int mt = 0; mt < 4; mt++) {
#pragma unroll
        for (int r = 0; r < 4; r++) {
            int row = row0 + mt * 16 + g * 4 + r;
            if (row < n) {
#pragma unroll
                for (int ct = 0; ct < CTW; ct++)
                    H[(size_t)row * NOUT + w * (16 * CTW) + ct * 16 + m] =
                        (_Float16)acc[mt][ct][r];
            }
        }
    }
}

// ---------- dispatch 1: part_count || gemm1 || Wt2/3 prep ----------
__global__ __launch_bounds__(256) void mega1(
    const int* __restrict__ dst, int* __restrict__ counts,
    unsigned short* __restrict__ lrank, int nb, int nblk, int e,
    const float* __restrict__ x, const float* __restrict__ W1,
    _Float16* __restrict__ bufH, int n, int gGemm,
    const float* __restrict__ W2, const float* __restrict__ W3,
    _Float16* __restrict__ Wt2, _Float16* __restrict__ Wt3) {
    __shared__ _Float16 Xs[64][136];
    __shared__ _Float16 Ws[128][136];
    __shared__ int c[256];
    int t = threadIdx.x, blk = blockIdx.x;

    if (blk < nblk) {  // ---- bucket histogram + local rank ----
        c[t] = 0;
        __syncthreads();
        int b0 = blk * CE;
#pragma unroll
        for (int j = 0; j < 16; j++) {
            int i = b0 + j * 256 + t;
            if (i < e) {
                int b = dst[i] >> 8;
                int r = atomicAdd(&c[b], 1);  // LDS atomic
                lrank[i] = (unsigned short)r;
            }
        }
        __syncthreads();
        if (t < nb) counts[(size_t)t * nblk + blk] = c[t];
        return;
    }
    if (blk < nblk + gGemm) {  // ---- gemm1 tile: stage W1 fp32 transposed ----
        for (int i = t; i < 128 * 128; i += 256) {
            int k = i >> 7, nn = i & 127;
            Ws[nn][k] = (_Float16)W1[i];  // 8-way LDS write conflict, one-time
        }
        gemm_tile<128, false>(x, Xs, Ws, bufH, n, blk - nblk, t);
        return;
    }
    // ---- Wt2/Wt3 prep (fp16 transposed) ----
    int i = (blk - nblk - gGemm) * 256 + t;
    if (i < 128 * 128) {
        int k = i >> 7, nn = i & 127;
        Wt2[(size_t)nn * 128 + k] = (_Float16)W2[i];
    } else if (i < 128 * 128 + 64 * 128) {
        int l = i - 128 * 128, k = l >> 6, nn = l & 63;
        Wt3[(size_t)nn * 128 + k] = (_Float16)W3[l];
    }
}

// ---------- dispatch 2: scatter; base self-scanned; block 0 exports bucket_beg ----------
__global__ __launch_bounds__(256) void part_scatter(const int* __restrict__ src,
                                                    const int* __restrict__ dst,
                                                    const float* __restrict__ ew,
                                                    const int* __restrict__ counts,
                                                    const unsigned short* __restrict__ lrank,
                                                    int2* __restrict__ arr1,
                                                    int* __restrict__ bucket_beg,
                                                    int nb, int nblk, int e) {
    __shared__ int tsum[256];
    __shared__ int lbase[256];  // nb <= 256 entries used
    int t = threadIdx.x, blk = blockIdx.x;
    int m = nb * nblk;
    int ch = (m + 255) / 256;
    int s0 = t * ch, s1 = min(s0 + ch, m);
    // pass A: per-thread chunk sums -> exclusive prefix
    int loc = 0;
    for (int i = s0; i < s1; i++) loc += counts[i];
    tsum[t] = loc;
    __syncthreads();
    for (int off = 1; off < 256; off <<= 1) {
        int cur = tsum[t];
        int add = (t >= off) ? tsum[t - off] : 0;
        __syncthreads();
        tsum[t] = cur + add;
        __syncthreads();
    }
    int run = (t == 0) ? 0 : tsum[t - 1];
    // pass B: walk chunk, capture prefix at idx == b*nblk + blk
    if (s0 < m) {
        int b = s0 / nblk, r = s0 - b * nblk;
        for (int i = s0; i < s1; i++) {
            if (r == blk) lbase[b] = run;
            run += counts[i];
            if (++r == nblk) { r = 0; b++; }
        }
    }
    __syncthreads();
    // block 0: lbase[b] is the bucket beginning -> export for bucket_csr
    if (blk == 0) {
        if (t < nb) bucket_beg[t] = lbase[t];
        if (t == 0) bucket_beg[nb] = e;
    }
    // edge scatter
    int b0 = blk * CE;
#pragma unroll
    for (int j = 0; j < 16; j++) {
        int i = b0 + j * 256 + t;
        if (i < e) {
            int d = dst[i];
            int pos = lbase[d >> 8] + lrank[i];
            arr1[pos] = make_int2((src[i] << 8) | (d & 255), __float_as_int(ew[i]));
        }
    }
}

// ---------- dispatch 3: per-bucket CSR finalize, rank by (dlow, src-quartile) ----------
__global__ __launch_bounds__(1024) void bucket_csr(const int2* __restrict__ arr1,
                                                   const int* __restrict__ bucket_beg,
                                                   unsigned short* __restrict__ rank2,
                                                   float* __restrict__ dinv,
                                                   int* __restrict__ row_ptr,
                                                   int2* __restrict__ ep,
                                                   int nb, int n, int e) {
    __shared__ unsigned long long pk[1024];  // cnt lo32 | fx-sum hi32, per (dlow,srcq)
    __shared__ int nbase[1024];
    __shared__ int ss[1024];
    __shared__ float ldsdinv[256];
    int t = threadIdx.x, b = blockIdx.x;
    int beg = bucket_beg[b];
    int end = bucket_beg[b + 1];
    pk[t] = 0ULL;
    __syncthreads();
    for (int i = beg + t; i < end; i += 1024) {
        int2 a = arr1[i];
        int ld4 = ((a.x & 255) << 2) | ((a.x >> 22) & 3);  // (dlow, src>>14)
        float w = __int_as_float(a.y);
        unsigned long long fx = (unsigned long long)(unsigned int)(w * FIX_SCALE + 0.5f);
        unsigned long long old = atomicAdd(&pk[ld4], (fx << 32) | 1ULL);  // LDS
        rank2[i] = (unsigned short)(old & 0xffffffffULL);
    }
    __syncthreads();
    int cnt = (int)(pk[t] & 0xffffffffULL);
    ss[t] = cnt;
    __syncthreads();
    for (int off = 1; off < 1024; off <<= 1) {
        int cur = ss[t];
        int add = (t >= off) ? ss[t - off] : 0;
        __syncthreads();
        ss[t] = cur + add;
        __syncthreads();
    }
    nbase[t] = ss[t] - cnt;
    __syncthreads();
    if (t < 256) {
        int d = b * 256 + t;
        if (d < n) {
            unsigned int fxs = 0;
#pragma unroll
            for (int q = 0; q < 4; q++) fxs += (unsigned int)(pk[t * 4 + q] >> 32);
            float dv = rsqrtf(1.0f + (float)fxs * (1.0f / FIX_SCALE));  // +1 self loop
            dinv[d] = dv;
            ldsdinv[t] = dv;
            row_ptr[d] = beg + nbase[t * 4];
        }
    }
    __syncthreads();
    for (int i = beg + t; i < end; i += 1024) {
        int2 a = arr1[i];
        int dlow = a.x & 255;
        int ld4 = (dlow << 2) | ((a.x >> 22) & 3);
        int pos = beg + nbase[ld4] + rank2[i];
        float w = __int_as_float(a.y) * ldsdinv[dlow];
        ep[pos] = make_int2(a.x >> 8, __float_as_int(w));  // src index, w*dinv[dst]
    }
}

// ---------- dispatch 4: ep -> (src byte offset, w*dinv[src]); row_ptr[N]=E ----------
__global__ void val_kernel(int2* __restrict__ ep, const float* __restrict__ dinv,
                           int* __restrict__ row_ptr, int n, int e) {
    int i = blockIdx.x * blockDim.x + threadIdx.x;
    if (i == 0) row_ptr[n] = e;
    if (i >= e) return;
    int2 a = ep[i];
    float w = __int_as_float(a.y) * dinv[a.x];
    ep[i] = make_int2(a.x << 8, __float_as_int(w));  // src*256 B (fp16 row, F=128)
}

// ---------- standalone MFMA gemm (layers 2,3: fp16 X, fp16 Wt) ----------
template <int NOUT>
__global__ __launch_bounds__(256) void mfma_gemm(const _Float16* __restrict__ X,
                                                 const _Float16* __restrict__ Wt,
                                                 _Float16* __restrict__ H, int n) {
    __shared__ _Float16 Xs[64][136];
    __shared__ _Float16 Ws[NOUT][136];
    int t = threadIdx.x;
    for (int i = t * 8; i < NOUT * K_IN; i += 2048) {
        int nn = i >> 7, k = i & 127;
        *(uint4*)&Ws[nn][k] = *(const uint4*)&Wt[i];
    }
    gemm_tile<NOUT, true>(X, Xs, Ws, H, n, blockIdx.x, t);
}

// ---------- aggregation: scalar ep loads, byte-offset gathers, fp32 accum ----------
template <int F, bool RELU, bool OF16>
__global__ __launch_bounds__(256) void agg_kernel(const __half* __restrict__ H,
                                                  const int* __restrict__ row_ptr,
                                                  const int2* __restrict__ ep,
                                                  const float* __restrict__ dinv,
                                                  const float* __restrict__ bias,
                                                  void* __restrict__ outv, int n) {
    constexpr int UN = 24;
    int wid = threadIdx.x >> 6;
    int lane = threadIdx.x & 63;
    int node = blockIdx.x * 4 + wid;
    if (node >= n) return;

    int start = __builtin_amdgcn_readfirstlane(row_ptr[node]);
    int end   = __builtin_amdgcn_readfirstlane(row_ptr[node + 1]);
    float di = dinv[node];
    float sw = di * di;

    const unsigned lb = (unsigned)lane * (F == 128 ? 4u : 2u);  // lane byte offset

    float a0, a1;
    if (F == 128) {
        float2 s2 = __half22float2(((const __half2*)(H + (size_t)node * 128))[lane]);
        a0 = s2.x * sw; a1 = s2.y * sw;
    } else {
        a0 = __half2float(H[(size_t)node * 64 + lane]) * sw; a1 = 0.f;
    }

    int len = end - start;
    int nf = len / UN;
    for (int b = 0; b < nf; b++) {
        int p0 = start + b * UN;
        int2 e[UN];
#pragma unroll
        for (int u = 0; u < UN; u++) e[u] = ep[p0 + u];  // uniform addr -> s_load
        __half2 v2[UN];
        __half v1[UN];
#pragma unroll
        for (int u = 0; u < UN; u++) {
            unsigned off = (unsigned)e[u].x;
            if (F == 64) off >>= 1;
            if (F == 128) v2[u] = *(const __half2*)((const char*)H + (off + lb));
            else          v1[u] = *(const __half*)((const char*)H + (off + lb));
        }
#pragma unroll
        for (int u = 0; u < UN; u++) {
            float w = __int_as_float(e[u].y);
            if (F == 128) {
                float2 f = __half22float2(v2[u]);
                a0 += w * f.x; a1 += w * f.y;
            } else {
                a0 += w * __half2float(v1[u]);
            }
        }
    }
    int base = start + nf * UN;
    if (base < end) {  // single predicated tail batch (uniform predicates)
        int2 e[UN];
#pragma unroll
        for (int u = 0; u < UN; u++) {
            int p = base + u;
            int q = (p < end) ? p : end - 1;
            int2 t2 = ep[q];
            if (p >= end) t2.y = 0;
            e[u] = t2;
        }
        __half2 v2[UN];
        __half v1[UN];
#pragma unroll
        for (int u = 0; u < UN; u++) {
            unsigned off = (unsigned)e[u].x;
            if (F == 64) off >>= 1;
            if (F == 128) v2[u] = *(const __half2*)((const char*)H + (off + lb));
            else          v1[u] = *(const __half*)((const char*)H + (off + lb));
        }
#pragma unroll
        for (int u = 0; u < UN; u++) {
            float w = __int_as_float(e[u].y);
            if (F == 128) {
                float2 f = __half22float2(v2[u]);
                a0 += w * f.x; a1 += w * f.y;
            } else {
                a0 += w * __half2float(v1[u]);
            }
        }
    }

    if (F == 128) {
        float o0 = a0 + bias[lane * 2];
        float o1 = a1 + bias[lane * 2 + 1];
        if (RELU) { o0 = fmaxf(o0, 0.f); o1 = fmaxf(o1, 0.f); }
        if (OF16) {
            ((__half2*)outv)[(size_t)node * 64 + lane] = __floats2half2_rn(o0, o1);
        } else {
            *(float2*)((float*)outv + (size_t)node * 128 + lane * 2) = make_float2(o0, o1);
        }
    } else {
        float o = a0 + bias[lane];
        if (RELU) o = fmaxf(o, 0.f);
        if (OF16) ((__half*)outv)[(size_t)node * 64 + lane] = __float2half(o);
        else      ((float*)outv)[(size_t)node * 64 + lane] = o;
    }
}

// ---------- launch ----------

extern "C" void kernel_launch(void* const* d_in, const int* in_sizes, int n_in,
                              void* d_out, int out_size, void* d_ws, size_t ws_size,
                              hipStream_t stream) {
    const float* x   = (const float*)d_in[0];
    const int*   ei  = (const int*)d_in[1];   // int32 (JAX x64 disabled)
    const float* ew  = (const float*)d_in[2];
    const float* W1  = (const float*)d_in[3];
    const float* b1  = (const float*)d_in[4];
    const float* W2  = (const float*)d_in[5];
    const float* b2  = (const float*)d_in[6];
    const float* W3  = (const float*)d_in[7];
    const float* b3  = (const float*)d_in[8];
    float* out = (float*)d_out;

    const int N = in_sizes[0] / K_IN;
    const int E = in_sizes[2];
    const int* src = ei;
    const int* dst = ei + E;

    const int NB   = (N + 255) >> 8;     // buckets, <=256
    const int NBLK = (E + CE - 1) / CE;  // partition blocks
    const int NWT  = (128 * 128 + 64 * 128 + 255) / 256;  // Wt2/3 prep blocks

    char* w = (char*)d_ws;
    auto alloc = [&](size_t bytes) {
        void* p = (void*)w;
        w += (bytes + 255) & ~(size_t)255;
        return p;
    };
    int*            counts = (int*)alloc((size_t)NB * NBLK * 4);
    int*            bucket_beg = (int*)alloc((size_t)(NB + 1) * 4);
    unsigned short* lrank  = (unsigned short*)alloc((size_t)E * 2);  // reused as rank2
    int2*           arr1   = (int2*)alloc((size_t)E * 8);
    float*          dinv   = (float*)alloc((size_t)N * 4);
    int*            row_ptr= (int*)alloc((size_t)(N + 1) * 4);
    int2*           ep     = (int2*)alloc((size_t)E * 8);
    _Float16*       Wt2    = (_Float16*)alloc(128 * 128 * 2);
    _Float16*       Wt3    = (_Float16*)alloc(64 * 128 * 2);
    _Float16*       bufH   = (_Float16*)alloc((size_t)N * 128 * 2);  // gemm out
    _Float16*       bufX   = (_Float16*)alloc((size_t)N * 128 * 2);  // agg out (fp16)

    int gGemm = (N + 63) / 64;
    int gAgg  = (N + 3) / 4;

    // 1: part_count || gemm1 (x@W1, W1 transposed in-staging) || Wt2/3 prep
    mega1<<<NBLK + gGemm + NWT, 256, 0, stream>>>(dst, counts, lrank, NB, NBLK, E,
                                                  x, W1, bufH, N, gGemm, W2, W3, Wt2, Wt3);
    // 2: scatter (self-scanned bases; block 0 exports bucket_beg)
    part_scatter<<<NBLK, 256, 0, stream>>>(src, dst, ew, counts, lrank, arr1,
                                           bucket_beg, NB, NBLK, E);
    // 3: per-bucket CSR finalize (src-quartile ordering within rows)
    bucket_csr<<<NB, 1024, 0, stream>>>(arr1, bucket_beg, lrank, dinv, row_ptr, ep,
                                        NB, N, E);
    // 4: val
    val_kernel<<<(E + 255) / 256, 256, 0, stream>>>(ep, dinv, row_ptr, N, E);
    // 5-9: layers
    agg_kernel<128, true, true><<<gAgg, 256, 0, stream>>>((const __half*)bufH, row_ptr, ep,
                                                          dinv, b1, bufX, N);
    mfma_gemm<128><<<gGemm, 256, 0, stream>>>(bufX, Wt2, bufH, N);
    agg_kernel<128, true, true><<<gAgg, 256, 0, stream>>>((const __half*)bufH, row_ptr, ep,
                                                          dinv, b2, bufX, N);
    mfma_gemm<64><<<gGemm, 256, 0, stream>>>(bufX, Wt3, bufH, N);
    agg_kernel<64, false, false><<<gAgg, 256, 0, stream>>>((const __half*)bufH, row_ptr, ep,
                                                           dinv, b3, out, N);
}

// Round 13
// 322.440 us; speedup vs baseline: 11.7405x; 1.2755x over previous
//
#include <hip/hip_runtime.h>
#include <hip/hip_bf16.h>
#include <hip/hip_fp16.h>

// GCN 3-layer. R13: revert R11's "self-scan" from part_scatter (120us at 16%
// occupancy: per-block 300-iter serial count-walk) back to R10's 3-kernel
// parallel scan + 1024-thread scatter reading base[] directly; bucket_csr
// reads beg/end from base[b*nblk] (2 scalar loads). KEEP: mega1 fusion
// (part_count || gemm1 in-staging W1 transpose || Wt2/3 prep), R11's
// src-quartile row ordering (worth ~5us/agg), scalar-ep agg UN=24.

#define K_IN 128              // all layers have in_features == 128
#define FIX_SCALE 8388608.0f  // 2^23 fixed point for ew sums
#define CE 4096               // edges per partition block

typedef _Float16 f16x8 __attribute__((ext_vector_type(8)));
typedef float f32x4 __attribute__((ext_vector_type(4)));

// ---------- shared gemm tile body ----------
template <int NOUT, bool XF16>
__device__ __forceinline__ void gemm_tile(const void* __restrict__ Xv,
                                          _Float16 (*Xs)[136],
                                          _Float16 (*Ws)[136],
                                          _Float16* __restrict__ H,
                                          int n, int tile, int t) {
    constexpr int CTW = NOUT / 64;  // col-tiles per wave
    int row0 = tile * 64;
    if (XF16) {
        const _Float16* X = (const _Float16*)Xv;
        for (int i = t * 8; i < 64 * K_IN; i += 2048) {
            int r = i >> 7, k = i & 127;
            int row = row0 + r;
            uint4 v = make_uint4(0u, 0u, 0u, 0u);
            if (row < n) v = *(const uint4*)(X + (size_t)row * K_IN + k);
            *(uint4*)&Xs[r][k] = v;
        }
    } else {
        const float* X = (const float*)Xv;
        for (int i = t * 4; i < 64 * K_IN; i += 1024) {
            int r = i >> 7, k = i & 127;
            int row = row0 + r;
            float4 x4 = make_float4(0.f, 0.f, 0.f, 0.f);
            if (row < n) x4 = *(const float4*)(X + (size_t)row * K_IN + k);
            union { _Float16 h[4]; uint2 u; } uu;
            uu.h[0] = (_Float16)x4.x; uu.h[1] = (_Float16)x4.y;
            uu.h[2] = (_Float16)x4.z; uu.h[3] = (_Float16)x4.w;
            *(uint2*)&Xs[r][k] = uu.u;
        }
    }
    __syncthreads();

    int lane = t & 63, w = t >> 6;
    int m = lane & 15, g = lane >> 4;
    f32x4 acc[4][CTW];
#pragma unroll
    for (int mt = 0; mt < 4; mt++)
#pragma unroll
        for (int ct = 0; ct < CTW; ct++) acc[mt][ct] = (f32x4){0.f, 0.f, 0.f, 0.f};

#pragma unroll
    for (int kt = 0; kt < 4; kt++) {
        int kb = kt * 32 + g * 8;
        f16x8 a[4];
#pragma unroll
        for (int mt = 0; mt < 4; mt++) a[mt] = *(const f16x8*)&Xs[mt * 16 + m][kb];
#pragma unroll
        for (int ct = 0; ct < CTW; ct++) {
            int nn = w * (16 * CTW) + ct * 16 + m;
            f16x8 b = *(const f16x8*)&Ws[nn][kb];
#pragma unroll
            for (int mt = 0; mt < 4; mt++)
                acc[mt][ct] = __builtin_amdgcn_mfma_f32_16x16x32_f16(a[mt], b, acc[mt][ct], 0, 0, 0);
        }
    }

#pragma unroll
    for (int mt = 0; mt < 4; mt++) {
#pragma unroll
        for (int r = 0; r < 4; r++) {
            int row = row0 + mt * 16 + g * 4 + r;
            if (row < n) {
#pragma unroll
                for (int ct = 0; ct < CTW; ct++)
                    H[(size_t)row * NOUT + w * (16 * CTW) + ct * 16 + m] =
                        (_Float16)acc[mt][ct][r];
            }
        }
    }
}

// ---------- dispatch 1: part_count || gemm1 || Wt2/3 prep ----------
__global__ __launch_bounds__(256) void mega1(
    const int* __restrict__ dst, int* __restrict__ counts,
    unsigned short* __restrict__ lrank, int nb, int nblk, int e,
    const float* __restrict__ x, const float* __restrict__ W1,
    _Float16* __restrict__ bufH, int n, int gGemm,
    const float* __restrict__ W2, const float* __restrict__ W3,
    _Float16* __restrict__ Wt2, _Float16* __restrict__ Wt3) {
    __shared__ _Float16 Xs[64][136];
    __shared__ _Float16 Ws[128][136];
    __shared__ int c[256];
    int t = threadIdx.x, blk = blockIdx.x;

    if (blk < nblk) {  // ---- bucket histogram + local rank ----
        c[t] = 0;
        __syncthreads();
        int b0 = blk * CE;
#pragma unroll
        for (int j = 0; j < 16; j++) {
            int i = b0 + j * 256 + t;
            if (i < e) {
                int b = dst[i] >> 8;
                int r = atomicAdd(&c[b], 1);  // LDS atomic
                lrank[i] = (unsigned short)r;
            }
        }
        __syncthreads();
        if (t < nb) counts[(size_t)t * nblk + blk] = c[t];
        return;
    }
    if (blk < nblk + gGemm) {  // ---- gemm1 tile: stage W1 fp32 transposed ----
        for (int i = t; i < 128 * 128; i += 256) {
            int k = i >> 7, nn = i & 127;
            Ws[nn][k] = (_Float16)W1[i];  // 8-way LDS write conflict, one-time
        }
        gemm_tile<128, false>(x, Xs, Ws, bufH, n, blk - nblk, t);
        return;
    }
    // ---- Wt2/Wt3 prep (fp16 transposed) ----
    int i = (blk - nblk - gGemm) * 256 + t;
    if (i < 128 * 128) {
        int k = i >> 7, nn = i & 127;
        Wt2[(size_t)nn * 128 + k] = (_Float16)W2[i];
    } else if (i < 128 * 128 + 64 * 128) {
        int l = i - 128 * 128, k = l >> 6, nn = l & 63;
        Wt3[(size_t)nn * 128 + k] = (_Float16)W3[l];
    }
}

// ---------- dispatches 2-4: parallel exclusive scan over counts[nb*nblk] ----------
__global__ __launch_bounds__(256) void reduce_kernel(const int* __restrict__ v,
                                                     int* __restrict__ bs, int m) {
    __shared__ int s[256];
    int t = threadIdx.x, i = blockIdx.x * 256 + t;
    s[t] = (i < m) ? v[i] : 0;
    __syncthreads();
    for (int off = 128; off > 0; off >>= 1) {
        if (t < off) s[t] += s[t + off];
        __syncthreads();
    }
    if (t == 0) bs[blockIdx.x] = s[0];
}

__global__ __launch_bounds__(1024) void scanb1024(const int* __restrict__ bs,
                                                  int* __restrict__ bo, int nbb) {
    __shared__ int s[1024];
    int t = threadIdx.x;
    s[t] = (t < nbb) ? bs[t] : 0;
    __syncthreads();
    for (int off = 1; off < 1024; off <<= 1) {
        int cur = s[t];
        int add = (t >= off) ? s[t - off] : 0;
        __syncthreads();
        s[t] = cur + add;
        __syncthreads();
    }
    if (t < nbb) bo[t] = (t == 0) ? 0 : s[t - 1];
}

__global__ __launch_bounds__(256) void scanw_kernel(const int* __restrict__ v,
                                                    const int* __restrict__ bo,
                                                    int* __restrict__ outp, int m) {
    __shared__ int s[256];
    int t = threadIdx.x, i = blockIdx.x * 256 + t;
    int c = (i < m) ? v[i] : 0;
    s[t] = c;
    __syncthreads();
    for (int off = 1; off < 256; off <<= 1) {
        int cur = s[t];
        int add = (t >= off) ? s[t - off] : 0;
        __syncthreads();
        s[t] = cur + add;
        __syncthreads();
    }
    if (i < m) outp[i] = bo[blockIdx.x] + (s[t] - c);  // exclusive
}

// ---------- dispatch 5: scatter into bucket-sorted order (reads base[] direct) ----------
__global__ __launch_bounds__(1024) void part_scatter(const int* __restrict__ src,
                                                     const int* __restrict__ dst,
                                                     const float* __restrict__ ew,
                                                     const int* __restrict__ base,
                                                     const unsigned short* __restrict__ lrank,
                                                     int2* __restrict__ arr1,
                                                     int nblk, int e) {
    int t = threadIdx.x, blk = blockIdx.x;
    int b0 = blk * CE;
#pragma unroll
    for (int j = 0; j < 4; j++) {
        int i = b0 + j * 1024 + t;
        if (i < e) {
            int d = dst[i];
            int b = d >> 8;
            int pos = base[(size_t)b * nblk + blk] + lrank[i];
            arr1[pos] = make_int2((src[i] << 8) | (d & 255), __float_as_int(ew[i]));
        }
    }
}

// ---------- dispatch 6: per-bucket CSR finalize, rank by (dlow, src-quartile) ----------
__global__ __launch_bounds__(1024) void bucket_csr(const int2* __restrict__ arr1,
                                                   const int* __restrict__ base,
                                                   unsigned short* __restrict__ rank2,
                                                   float* __restrict__ dinv,
                                                   int* __restrict__ row_ptr,
                                                   int2* __restrict__ ep,
                                                   int nb, int nblk, int n, int e) {
    __shared__ unsigned long long pk[1024];  // cnt lo32 | fx-sum hi32, per (dlow,srcq)
    __shared__ int nbase[1024];
    __shared__ int ss[1024];
    __shared__ float ldsdinv[256];
    int t = threadIdx.x, b = blockIdx.x;
    int beg = base[(size_t)b * nblk];
    int end = (b + 1 < nb) ? base[(size_t)(b + 1) * nblk] : e;
    pk[t] = 0ULL;
    __syncthreads();
    for (int i = beg + t; i < end; i += 1024) {
        int2 a = arr1[i];
        int ld4 = ((a.x & 255) << 2) | ((a.x >> 22) & 3);  // (dlow, src>>14)
        float w = __int_as_float(a.y);
        unsigned long long fx = (unsigned long long)(unsigned int)(w * FIX_SCALE + 0.5f);
        unsigned long long old = atomicAdd(&pk[ld4], (fx << 32) | 1ULL);  // LDS
        rank2[i] = (unsigned short)(old & 0xffffffffULL);
    }
    __syncthreads();
    int cnt = (int)(pk[t] & 0xffffffffULL);
    ss[t] = cnt;
    __syncthreads();
    for (int off = 1; off < 1024; off <<= 1) {
        int cur = ss[t];
        int add = (t >= off) ? ss[t - off] : 0;
        __syncthreads();
        ss[t] = cur + add;
        __syncthreads();
    }
    nbase[t] = ss[t] - cnt;
    __syncthreads();
    if (t < 256) {
        int d = b * 256 + t;
        if (d < n) {
            unsigned int fxs = 0;
#pragma unroll
            for (int q = 0; q < 4; q++) fxs += (unsigned int)(pk[t * 4 + q] >> 32);
            float dv = rsqrtf(1.0f + (float)fxs * (1.0f / FIX_SCALE));  // +1 self loop
            dinv[d] = dv;
            ldsdinv[t] = dv;
            row_ptr[d] = beg + nbase[t * 4];
        }
    }
    __syncthreads();
    for (int i = beg + t; i < end; i += 1024) {
        int2 a = arr1[i];
        int dlow = a.x & 255;
        int ld4 = (dlow << 2) | ((a.x >> 22) & 3);
        int pos = beg + nbase[ld4] + rank2[i];
        float w = __int_as_float(a.y) * ldsdinv[dlow];
        ep[pos] = make_int2(a.x >> 8, __float_as_int(w));  // src index, w*dinv[dst]
    }
}

// ---------- dispatch 7: ep -> (src byte offset, w*dinv[src]); row_ptr[N]=E ----------
__global__ void val_kernel(int2* __restrict__ ep, const float* __restrict__ dinv,
                           int* __restrict__ row_ptr, int n, int e) {
    int i = blockIdx.x * blockDim.x + threadIdx.x;
    if (i == 0) row_ptr[n] = e;
    if (i >= e) return;
    int2 a = ep[i];
    float w = __int_as_float(a.y) * dinv[a.x];
    ep[i] = make_int2(a.x << 8, __float_as_int(w));  // src*256 B (fp16 row, F=128)
}

// ---------- standalone MFMA gemm (layers 2,3: fp16 X, fp16 Wt) ----------
template <int NOUT>
__global__ __launch_bounds__(256) void mfma_gemm(const _Float16* __restrict__ X,
                                                 const _Float16* __restrict__ Wt,
                                                 _Float16* __restrict__ H, int n) {
    __shared__ _Float16 Xs[64][136];
    __shared__ _Float16 Ws[NOUT][136];
    int t = threadIdx.x;
    for (int i = t * 8; i < NOUT * K_IN; i += 2048) {
        int nn = i >> 7, k = i & 127;
        *(uint4*)&Ws[nn][k] = *(const uint4*)&Wt[i];
    }
    gemm_tile<NOUT, true>(X, Xs, Ws, H, n, blockIdx.x, t);
}

// ---------- aggregation: scalar ep loads, byte-offset gathers, fp32 accum ----------
template <int F, bool RELU, bool OF16>
__global__ __launch_bounds__(256) void agg_kernel(const __half* __restrict__ H,
                                                  const int* __restrict__ row_ptr,
                                                  const int2* __restrict__ ep,
                                                  const float* __restrict__ dinv,
                                                  const float* __restrict__ bias,
                                                  void* __restrict__ outv, int n) {
    constexpr int UN = 24;
    int wid = threadIdx.x >> 6;
    int lane = threadIdx.x & 63;
    int node = blockIdx.x * 4 + wid;
    if (node >= n) return;

    int start = __builtin_amdgcn_readfirstlane(row_ptr[node]);
    int end   = __builtin_amdgcn_readfirstlane(row_ptr[node + 1]);
    float di = dinv[node];
    float sw = di * di;

    const unsigned lb = (unsigned)lane * (F == 128 ? 4u : 2u);  // lane byte offset

    float a0, a1;
    if (F == 128) {
        float2 s2 = __half22float2(((const __half2*)(H + (size_t)node * 128))[lane]);
        a0 = s2.x * sw; a1 = s2.y * sw;
    } else {
        a0 = __half2float(H[(size_t)node * 64 + lane]) * sw; a1 = 0.f;
    }

    int len = end - start;
    int nf = len / UN;
    for (int b = 0; b < nf; b++) {
        int p0 = start + b * UN;
        int2 e[UN];
#pragma unroll
        for (int u = 0; u < UN; u++) e[u] = ep[p0 + u];  // uniform addr -> s_load
        __half2 v2[UN];
        __half v1[UN];
#pragma unroll
        for (int u = 0; u < UN; u++) {
            unsigned off = (unsigned)e[u].x;
            if (F == 64) off >>= 1;
            if (F == 128) v2[u] = *(const __half2*)((const char*)H + (off + lb));
            else          v1[u] = *(const __half*)((const char*)H + (off + lb));
        }
#pragma unroll
        for (int u = 0; u < UN; u++) {
            float w = __int_as_float(e[u].y);
            if (F == 128) {
                float2 f = __half22float2(v2[u]);
                a0 += w * f.x; a1 += w * f.y;
            } else {
                a0 += w * __half2float(v1[u]);
            }
        }
    }
    int base = start + nf * UN;
    if (base < end) {  // single predicated tail batch (uniform predicates)
        int2 e[UN];
#pragma unroll
        for (int u = 0; u < UN; u++) {
            int p = base + u;
            int q = (p < end) ? p : end - 1;
            int2 t2 = ep[q];
            if (p >= end) t2.y = 0;
            e[u] = t2;
        }
        __half2 v2[UN];
        __half v1[UN];
#pragma unroll
        for (int u = 0; u < UN; u++) {
            unsigned off = (unsigned)e[u].x;
            if (F == 64) off >>= 1;
            if (F == 128) v2[u] = *(const __half2*)((const char*)H + (off + lb));
            else          v1[u] = *(const __half*)((const char*)H + (off + lb));
        }
#pragma unroll
        for (int u = 0; u < UN; u++) {
            float w = __int_as_float(e[u].y);
            if (F == 128) {
                float2 f = __half22float2(v2[u]);
                a0 += w * f.x; a1 += w * f.y;
            } else {
                a0 += w * __half2float(v1[u]);
            }
        }
    }

    if (F == 128) {
        float o0 = a0 + bias[lane * 2];
        float o1 = a1 + bias[lane * 2 + 1];
        if (RELU) { o0 = fmaxf(o0, 0.f); o1 = fmaxf(o1, 0.f); }
        if (OF16) {
            ((__half2*)outv)[(size_t)node * 64 + lane] = __floats2half2_rn(o0, o1);
        } else {
            *(float2*)((float*)outv + (size_t)node * 128 + lane * 2) = make_float2(o0, o1);
        }
    } else {
        float o = a0 + bias[lane];
        if (RELU) o = fmaxf(o, 0.f);
        if (OF16) ((__half*)outv)[(size_t)node * 64 + lane] = __float2half(o);
        else      ((float*)outv)[(size_t)node * 64 + lane] = o;
    }
}

// ---------- launch ----------

extern "C" void kernel_launch(void* const* d_in, const int* in_sizes, int n_in,
                              void* d_out, int out_size, void* d_ws, size_t ws_size,
                              hipStream_t stream) {
    const float* x   = (const float*)d_in[0];
    const int*   ei  = (const int*)d_in[1];   // int32 (JAX x64 disabled)
    const float* ew  = (const float*)d_in[2];
    const float* W1  = (const float*)d_in[3];
    const float* b1  = (const float*)d_in[4];
    const float* W2  = (const float*)d_in[5];
    const float* b2  = (const float*)d_in[6];
    const float* W3  = (const float*)d_in[7];
    const float* b3  = (const float*)d_in[8];
    float* out = (float*)d_out;

    const int N = in_sizes[0] / K_IN;
    const int E = in_sizes[2];
    const int* src = ei;
    const int* dst = ei + E;

    const int NB   = (N + 255) >> 8;     // buckets, <=256
    const int NBLK = (E + CE - 1) / CE;  // partition blocks
    const int M    = NB * NBLK;
    const int NBB  = (M + 255) / 256;    // scan blocks, <=1024
    const int NWT  = (128 * 128 + 64 * 128 + 255) / 256;  // Wt2/3 prep blocks

    char* w = (char*)d_ws;
    auto alloc = [&](size_t bytes) {
        void* p = (void*)w;
        w += (bytes + 255) & ~(size_t)255;
        return p;
    };
    int*            counts = (int*)alloc((size_t)M * 4);
    int*            base   = (int*)alloc((size_t)M * 4);
    int*            bsM    = (int*)alloc((size_t)NBB * 4);
    int*            boM    = (int*)alloc((size_t)NBB * 4);
    unsigned short* lrank  = (unsigned short*)alloc((size_t)E * 2);  // reused as rank2
    int2*           arr1   = (int2*)alloc((size_t)E * 8);
    float*          dinv   = (float*)alloc((size_t)N * 4);
    int*            row_ptr= (int*)alloc((size_t)(N + 1) * 4);
    int2*           ep     = (int2*)alloc((size_t)E * 8);
    _Float16*       Wt2    = (_Float16*)alloc(128 * 128 * 2);
    _Float16*       Wt3    = (_Float16*)alloc(64 * 128 * 2);
    _Float16*       bufH   = (_Float16*)alloc((size_t)N * 128 * 2);  // gemm out
    _Float16*       bufX   = (_Float16*)alloc((size_t)N * 128 * 2);  // agg out (fp16)

    int gGemm = (N + 63) / 64;
    int gAgg  = (N + 3) / 4;

    // 1: part_count || gemm1 (x@W1, W1 transposed in-staging) || Wt2/3 prep
    mega1<<<NBLK + gGemm + NWT, 256, 0, stream>>>(dst, counts, lrank, NB, NBLK, E,
                                                  x, W1, bufH, N, gGemm, W2, W3, Wt2, Wt3);
    // 2-4: parallel scan of counts -> base
    reduce_kernel<<<NBB, 256, 0, stream>>>(counts, bsM, M);
    scanb1024<<<1, 1024, 0, stream>>>(bsM, boM, NBB);
    scanw_kernel<<<NBB, 256, 0, stream>>>(counts, boM, base, M);
    // 5: scatter
    part_scatter<<<NBLK, 1024, 0, stream>>>(src, dst, ew, base, lrank, arr1, NBLK, E);
    // 6: per-bucket CSR finalize (src-quartile ordering within rows)
    bucket_csr<<<NB, 1024, 0, stream>>>(arr1, base, lrank, dinv, row_ptr, ep,
                                        NB, NBLK, N, E);
    // 7: val
    val_kernel<<<(E + 255) / 256, 256, 0, stream>>>(ep, dinv, row_ptr, N, E);
    // 8-12: layers
    agg_kernel<128, true, true><<<gAgg, 256, 0, stream>>>((const __half*)bufH, row_ptr, ep,
                                                          dinv, b1, bufX, N);
    mfma_gemm<128><<<gGemm, 256, 0, stream>>>(bufX, Wt2, bufH, N);
    agg_kernel<128, true, true><<<gAgg, 256, 0, stream>>>((const __half*)bufH, row_ptr, ep,
                                                          dinv, b2, bufX, N);
    mfma_gemm<64><<<gGemm, 256, 0, stream>>>(bufX, Wt3, bufH, N);
    agg_kernel<64, false, false><<<gAgg, 256, 0, stream>>>((const __half*)bufH, row_ptr, ep,
                                                           dinv, b3, out, N);
}